// Round 3
// baseline (283.754 us; speedup 1.0000x reference)
//
#include <hip/hip_runtime.h>
#include <cstdint>
#include <cstddef>

namespace {

constexpr int B = 8, NSEQ = 1024, C = 768, H = 12, D = 64, N3 = 2304;
constexpr float SCALE = 0.125f;
constexpr size_t QKV_ELEMS = (size_t)B * H * NSEQ * D;   // 6291456 per tensor

using f32x4 = __attribute__((ext_vector_type(4))) float;
using s16x8 = __attribute__((ext_vector_type(8))) short;

__device__ __forceinline__ unsigned short f2bf(float f) {
  union { float f; uint32_t u; } v; v.f = f;
  const uint32_t r = v.u + 0x7FFFu + ((v.u >> 16) & 1u);   // RNE
  return (unsigned short)(r >> 16);
}
__device__ __forceinline__ float bf2f(unsigned short s) {
  union { uint32_t u; float f; } v; v.u = ((uint32_t)s) << 16;
  return v.f;
}
__device__ __forceinline__ void gload_lds16(const void* g, void* l) {
  __builtin_amdgcn_global_load_lds(
      (const __attribute__((address_space(1))) uint32_t*)g,
      (__attribute__((address_space(3))) uint32_t*)l, 16, 0, 0);
}

// ---------------------------------------------------------------------------
// x -> bf16
// ---------------------------------------------------------------------------
__global__ __launch_bounds__(256)
void cvt_x(const float* __restrict__ x, unsigned short* __restrict__ xb, int n4) {
  const int stride = gridDim.x * 256;
  for (int idx = blockIdx.x * 256 + threadIdx.x; idx < n4; idx += stride) {
    const float4 v = ((const float4*)x)[idx];
    ushort4 o;
    o.x = f2bf(v.x); o.y = f2bf(v.y); o.z = f2bf(v.z); o.w = f2bf(v.w);
    ((ushort4*)xb)[idx] = o;
  }
}

// ---------------------------------------------------------------------------
// W[K][N] fp32 -> Wt[N][K] bf16
// ---------------------------------------------------------------------------
__global__ __launch_bounds__(256)
void transp_cvt(const float* __restrict__ w, unsigned short* __restrict__ wt,
                int K, int N) {
  __shared__ float t[32][33];
  const int n0 = blockIdx.x << 5, k0 = blockIdx.y << 5;
  const int tid = threadIdx.x;
  #pragma unroll
  for (int r = 0; r < 4; ++r) {
    const int e = (r << 8) + tid;
    const int kk = e >> 5, nn = e & 31;
    t[kk][nn] = w[(size_t)(k0 + kk) * N + n0 + nn];
  }
  __syncthreads();
  #pragma unroll
  for (int r = 0; r < 4; ++r) {
    const int e = (r << 8) + tid;
    const int nn = e >> 5, kk = e & 31;
    wt[(size_t)(n0 + nn) * K + k0 + kk] = f2bf(t[kk][nn]);
  }
}

// ---------------------------------------------------------------------------
// bf16 MFMA GEMM: out = A[M][768] @ Wt[N][768]^T + bias
// 128x128 tile, BK=64, 4 waves, XOR-swizzled LDS via pre-permuted source.
// 1D grid with bijective XCD swizzle; NT = tiles along N.
// MODE 0: scatter q/k bf16 [bh][n][d] and v^T bf16 [bh][d][n]
// MODE 1: fp32 row-major out
// ---------------------------------------------------------------------------
template<int MODE>
__global__ __launch_bounds__(256, 2)
void gemm_bf16(const unsigned short* __restrict__ A,
               const unsigned short* __restrict__ Wt,
               const float* __restrict__ bias,
               unsigned short* __restrict__ qp, unsigned short* __restrict__ kp,
               unsigned short* __restrict__ vt, float* __restrict__ out32,
               int N, int NT) {
  constexpr int K = 768;
  __shared__ short As[128 * 64];
  __shared__ short Bs[128 * 64];
  const int tid = threadIdx.x;
  const int wid = tid >> 6, lane = tid & 63;
  const int wm = wid >> 1, wn = wid & 1;
  const int lg = lane >> 4, lr = lane & 15;

  // bijective XCD swizzle (grid % 8 == 0)
  const int cpx = gridDim.x >> 3;
  const int logical = (blockIdx.x & 7) * cpx + (blockIdx.x >> 3);
  const int bx = logical % NT, by = logical / NT;
  const int m0 = by << 7, n0 = bx << 7;

  f32x4 acc[4][4] = {};

  for (int k0 = 0; k0 < K; k0 += 64) {
    __syncthreads();
    #pragma unroll
    for (int r = 0; r < 4; ++r) {
      const int c = (r << 8) + tid;
      const int row = c >> 3, g8 = c & 7;
      const int gp = g8 ^ (row & 7);                      // pre-permuted source
      const int ldsoff = (((r << 8) + (wid << 6)) << 3);  // wave-uniform, shorts
      gload_lds16(A + (size_t)(m0 + row) * K + k0 + (gp << 3), (void*)(As + ldsoff));
      gload_lds16(Wt + (size_t)(n0 + row) * K + k0 + (gp << 3), (void*)(Bs + ldsoff));
    }
    __syncthreads();
    #pragma unroll
    for (int kc = 0; kc < 2; ++kc) {
      s16x8 af[4], bf[4];
      #pragma unroll
      for (int i = 0; i < 4; ++i) {
        const int ra = (wm << 6) + (i << 4) + lr;
        const int ca = ((kc << 2) + lg) ^ (ra & 7);
        af[i] = *(const s16x8*)(As + (ra << 6) + (ca << 3));
        const int rb = (wn << 6) + (i << 4) + lr;
        const int cb = ((kc << 2) + lg) ^ (rb & 7);
        bf[i] = *(const s16x8*)(Bs + (rb << 6) + (cb << 3));
      }
      #pragma unroll
      for (int i = 0; i < 4; ++i)
        #pragma unroll
        for (int j = 0; j < 4; ++j)
          acc[i][j] = __builtin_amdgcn_mfma_f32_16x16x32_bf16(af[i], bf[j], acc[i][j], 0, 0, 0);
    }
  }

  #pragma unroll
  for (int i = 0; i < 4; ++i) {
    const int m = m0 + (wm << 6) + (i << 4) + (lg << 2);
    #pragma unroll
    for (int j = 0; j < 4; ++j) {
      const int n = n0 + (wn << 6) + (j << 4) + lr;
      const float bv = bias[n];
      if (MODE == 0) {
        const int which = (n >= 1536) ? 2 : (n >= 768 ? 1 : 0);
        const int hh = (n - which * 768) >> 6;
        const int d = n & 63;
        const int b = m >> 10, ns = m & 1023;
        const size_t bh = (size_t)b * H + hh;
        if (which < 2) {
          unsigned short* dst = (which == 0 ? qp : kp) + (bh * NSEQ + ns) * D + d;
          #pragma unroll
          for (int rg = 0; rg < 4; ++rg)
            dst[(size_t)rg * D] = f2bf(acc[i][j][rg] + bv);
        } else {
          ushort4 pk;
          pk.x = f2bf(acc[i][j][0] + bv);
          pk.y = f2bf(acc[i][j][1] + bv);
          pk.z = f2bf(acc[i][j][2] + bv);
          pk.w = f2bf(acc[i][j][3] + bv);
          *(ushort4*)(vt + (bh * D + d) * NSEQ + ns) = pk;   // ns % 4 == 0
        }
      } else {
        float* dst = out32 + (size_t)m * N + n;
        #pragma unroll
        for (int rg = 0; rg < 4; ++rg)
          dst[(size_t)rg * N] = acc[i][j][rg] + bv;
      }
    }
  }
}

// ---------------------------------------------------------------------------
// Attention: block = (bh, 32 q-rows), 8 waves (512 thr).
// Wave (wq, ws): q-group wq*16, key/d subtile ws*16.
// QK^T -> sc bf16 LDS -> softmax (unnormalized e) -> PV -> aout -> attnw last
// (attnw stores issued at the end so no barrier ever drains them).
// LDS: 66KB sc (RS=1032) + 8KB kv + 128B -> 2 blocks/CU.
// ---------------------------------------------------------------------------
constexpr int RS = 1032;   // row stride (shorts): 16B-aligned rows, bank-spread

__global__ __launch_bounds__(512, 4)
void attn_mfma(const unsigned short* __restrict__ qg,
               const unsigned short* __restrict__ kg,
               const unsigned short* __restrict__ vtg,
               float* __restrict__ attnw,
               unsigned short* __restrict__ aout) {
  __shared__ short sc[32][RS];
  __shared__ short kv[64 * 64];
  __shared__ float invs[32];
  const int tid = threadIdx.x;
  const int wid = tid >> 6, lane = tid & 63;
  const int lg = lane >> 4, lr = lane & 15;
  const int wq = wid >> 2, ws = wid & 3;

  // bijective XCD swizzle: 3072 blocks, 384/XCD -> 12 bh per XCD (K/V L2-hot)
  const int logical = (blockIdx.x & 7) * 384 + (blockIdx.x >> 3);
  const int bh = logical >> 5;
  const int q0 = (logical & 31) << 5;
  const size_t kvbase = (size_t)bh * NSEQ * D;

  // Q fragments: lane holds q-row = wq*16+lr, k-slice kc*32 + lg*8
  s16x8 qf[2];
  #pragma unroll
  for (int kc = 0; kc < 2; ++kc)
    qf[kc] = *(const s16x8*)(qg + kvbase + (size_t)(q0 + (wq << 4) + lr) * D + (kc << 5) + (lg << 3));

  // ---- QK^T ----
  for (int j0 = 0; j0 < NSEQ; j0 += 64) {
    __syncthreads();
    {
      const int row = tid >> 3, g8 = tid & 7;
      gload_lds16(kg + kvbase + (size_t)(j0 + row) * D + ((g8 ^ (row & 7)) << 3),
                  (void*)(kv + (wid << 9)));
    }
    __syncthreads();
    f32x4 cacc = {};
    const int krow = (ws << 4) + lr;
    #pragma unroll
    for (int kc = 0; kc < 2; ++kc) {
      const int cg = ((kc << 2) + lg) ^ (krow & 7);
      const s16x8 kf = *(const s16x8*)(kv + (krow << 6) + (cg << 3));
      cacc = __builtin_amdgcn_mfma_f32_16x16x32_bf16(qf[kc], kf, cacc, 0, 0, 0);
    }
    const int jg = j0 + (ws << 4) + lr;
    #pragma unroll
    for (int rg = 0; rg < 4; ++rg)
      sc[(wq << 4) + (lg << 2) + rg][jg] = (short)f2bf(cacc[rg] * SCALE);
  }
  __syncthreads();

  // ---- softmax: each 16-thread group owns one row ----
  {
    const int row = tid >> 4, ql = tid & 15;
    float mx = -3.0e38f;
    #pragma unroll
    for (int c = 0; c < 8; ++c) {
      const s16x8 v = *(const s16x8*)(&sc[row][(ql << 3) + (c << 7)]);
      #pragma unroll
      for (int e = 0; e < 8; ++e) mx = fmaxf(mx, bf2f((unsigned short)v[e]));
    }
    #pragma unroll
    for (int off = 8; off > 0; off >>= 1) mx = fmaxf(mx, __shfl_xor(mx, off, 16));
    float s = 0.f;
    #pragma unroll
    for (int c = 0; c < 8; ++c) {
      s16x8 v = *(s16x8*)(&sc[row][(ql << 3) + (c << 7)]);
      #pragma unroll
      for (int e = 0; e < 8; ++e) {
        const float ev = __expf(bf2f((unsigned short)v[e]) - mx);
        s += ev;
        v[e] = (short)f2bf(ev);
      }
      *(s16x8*)(&sc[row][(ql << 3) + (c << 7)]) = v;
    }
    #pragma unroll
    for (int off = 8; off > 0; off >>= 1) s += __shfl_xor(s, off, 16);
    if (ql == 0) invs[row] = 1.0f / s;
  }
  __syncthreads();

  // ---- PV ----
  f32x4 oacc = {};
  for (int j0 = 0; j0 < NSEQ; j0 += 64) {
    __syncthreads();
    {
      const int row = tid >> 3, g8 = tid & 7;   // row = d
      gload_lds16(vtg + (size_t)bh * D * NSEQ + (size_t)row * NSEQ + j0 + ((g8 ^ (row & 7)) << 3),
                  (void*)(kv + (wid << 9)));
    }
    __syncthreads();
    const int drow = (ws << 4) + lr;
    #pragma unroll
    for (int kc = 0; kc < 2; ++kc) {
      const s16x8 pa = *(const s16x8*)(&sc[(wq << 4) + lr][j0 + (kc << 5) + (lg << 3)]);
      const int cg = ((kc << 2) + lg) ^ (drow & 7);
      const s16x8 vf = *(const s16x8*)(kv + (drow << 6) + (cg << 3));
      oacc = __builtin_amdgcn_mfma_f32_16x16x32_bf16(pa, vf, oacc, 0, 0, 0);
    }
  }

  // ---- aout (bf16) ----
  {
    const int b = bh / H, hh = bh - b * H;
    const int d = (ws << 4) + lr;
    #pragma unroll
    for (int rg = 0; rg < 4; ++rg) {
      const int qi = (wq << 4) + (lg << 2) + rg;
      aout[((size_t)b * NSEQ + q0 + qi) * C + hh * D + d] = f2bf(oacc[rg] * invs[qi]);
    }
  }

  // ---- attn_weights: last, stores never drained by a barrier ----
  {
    float* wbase = attnw + ((size_t)bh * NSEQ + q0) * NSEQ;
    #pragma unroll
    for (int r = 0; r < 8; ++r) {
      const int row = (r << 2) + (tid >> 7);
      const int colb = (tid & 127) << 3;
      const float iv = invs[row];
      const s16x8 e8 = *(const s16x8*)(&sc[row][colb]);
      float4 o0, o1;
      o0.x = bf2f((unsigned short)e8[0]) * iv; o0.y = bf2f((unsigned short)e8[1]) * iv;
      o0.z = bf2f((unsigned short)e8[2]) * iv; o0.w = bf2f((unsigned short)e8[3]) * iv;
      o1.x = bf2f((unsigned short)e8[4]) * iv; o1.y = bf2f((unsigned short)e8[5]) * iv;
      o1.z = bf2f((unsigned short)e8[6]) * iv; o1.w = bf2f((unsigned short)e8[7]) * iv;
      *(float4*)(wbase + (size_t)row * NSEQ + colb) = o0;
      *(float4*)(wbase + (size_t)row * NSEQ + colb + 4) = o1;
    }
  }
}

} // namespace

extern "C" void kernel_launch(void* const* d_in, const int* in_sizes, int n_in,
                              void* d_out, int out_size, void* d_ws, size_t ws_size,
                              hipStream_t stream) {
  const float* x      = (const float*)d_in[0];
  const float* qkv_w  = (const float*)d_in[1];
  const float* qkv_b  = (const float*)d_in[2];
  const float* proj_w = (const float*)d_in[3];
  const float* proj_b = (const float*)d_in[4];

  float* out   = (float*)d_out;                      // [8,1024,768] fp32
  float* attnw = out + (size_t)B * NSEQ * C;         // [8,12,1024,1024] fp32

  unsigned short* xb   = (unsigned short*)d_ws;             // [8192][768]
  unsigned short* wtq  = xb   + (size_t)8192 * 768;         // [2304][768]
  unsigned short* wtp  = wtq  + (size_t)2304 * 768;         // [768][768]
  unsigned short* qp   = wtp  + (size_t)768 * 768;          // [96][1024][64]
  unsigned short* kp   = qp   + QKV_ELEMS;
  unsigned short* vtp  = kp   + QKV_ELEMS;                  // [96][64][1024]
  unsigned short* wsao = vtp  + QKV_ELEMS;                  // [8192][768]

  cvt_x<<<1024, 256, 0, stream>>>(x, xb, (int)((size_t)8192 * 768 / 4));
  transp_cvt<<<dim3(N3 / 32, C / 32), 256, 0, stream>>>(qkv_w, wtq, C, N3);
  transp_cvt<<<dim3(C / 32, C / 32), 256, 0, stream>>>(proj_w, wtp, C, C);

  gemm_bf16<0><<<(N3 / 128) * (8192 / 128), 256, 0, stream>>>(
      xb, wtq, qkv_b, qp, kp, vtp, nullptr, N3, N3 / 128);

  attn_mfma<<<(NSEQ / 32) * (B * H), 512, 0, stream>>>(qp, kp, vtp, attnw, wsao);

  gemm_bf16<1><<<(C / 128) * (8192 / 128), 256, 0, stream>>>(
      wsao, wtp, proj_b, nullptr, nullptr, nullptr, out, C, C / 128);
}